// Round 1
// baseline (269.963 us; speedup 1.0000x reference)
//
#include <hip/hip_runtime.h>

#define N_NODES 50000
#define DEG     32
#define D_FEAT  128
#define D_OUT   256

// ---------------------------------------------------------------------------
// Kernel A: neighborhood mean aggregation.
// agg[n][f] = (1/32) * sum_d features[edges[n][d]][f]
// 256 threads/block = 8 nodes/block, 32 lanes per node, float4 per lane.
// N=50000 divisible by 8 -> no tail guard.
// ---------------------------------------------------------------------------
__global__ __launch_bounds__(256) void agg_kernel(
    const float* __restrict__ feat,
    const int*   __restrict__ edges,
    float*       __restrict__ agg)
{
    const int node = blockIdx.x * 8 + (threadIdx.x >> 5);
    const int f4   = threadIdx.x & 31;          // which float4 of the 128-dim row
    const int* e   = edges + node * DEG;

    float4 acc = make_float4(0.f, 0.f, 0.f, 0.f);
    #pragma unroll
    for (int d = 0; d < DEG; ++d) {
        const int idx = e[d];                   // broadcast within the 32-lane group
        const float4 v = ((const float4*)(feat + (size_t)idx * D_FEAT))[f4];
        acc.x += v.x; acc.y += v.y; acc.z += v.z; acc.w += v.w;
    }
    const float s = 1.0f / (float)DEG;
    acc.x *= s; acc.y *= s; acc.z *= s; acc.w *= s;
    ((float4*)(agg + (size_t)node * D_FEAT))[f4] = acc;
}

// ---------------------------------------------------------------------------
// Kernel B: out = relu(concat(feat, agg) @ W), W is [256][256] row-major.
// Tile: 64 nodes x 64 cols per block, 256 threads, 4x4 micro-tile/thread.
// K=256 staged through LDS in 4 chunks of 64. The concat never materializes:
// chunk 0,1 read from feat, chunk 2,3 from agg (uniform per chunk).
// LDS strides padded to 68 floats (4-aligned, rotates banks) -> worst case
// 2-way conflicts, which are free on gfx950.
// ---------------------------------------------------------------------------
#define TM  64
#define TN  64
#define KC  64
#define LDT 68

__global__ __launch_bounds__(256) void gemm_kernel(
    const float* __restrict__ feat,
    const float* __restrict__ agg,
    const float* __restrict__ W,
    float*       __restrict__ out)
{
    __shared__ float Atile[TM * LDT];
    __shared__ float Btile[KC * LDT];

    const int tid  = threadIdx.x;
    const int tx   = tid & 15;        // 16 cols of 4
    const int ty   = tid >> 4;        // 16 rows of 4
    const int m0   = blockIdx.x * TM;
    const int c0   = blockIdx.y * TN;

    const int lrow = tid >> 4;        // load row within a 16-row pass
    const int lcol = (tid & 15) * 4;  // load col group (float4)

    float acc[4][4] = {};

    for (int kc = 0; kc < 4; ++kc) {
        // chunk source: concat = [feat | agg] along K
        const float* src = (kc < 2) ? (feat + kc * 64) : (agg + (kc - 2) * 64);

        __syncthreads();   // protect previous iteration's LDS reads

        // ---- stage A (64 rows x 64 k) ----
        #pragma unroll
        for (int p = 0; p < 4; ++p) {
            const int r = p * 16 + lrow;
            int node = m0 + r;
            if (node >= N_NODES) node = N_NODES - 1;   // clamp; stores are guarded
            const float4 v = *(const float4*)(src + (size_t)node * D_FEAT + lcol);
            *(float4*)(&Atile[r * LDT + lcol]) = v;
        }
        // ---- stage B (64 k x 64 cols) ----
        #pragma unroll
        for (int p = 0; p < 4; ++p) {
            const int k = p * 16 + lrow;
            const float4 v = *(const float4*)(W + (size_t)(kc * 64 + k) * D_OUT + c0 + lcol);
            *(float4*)(&Btile[k * LDT + lcol]) = v;
        }
        __syncthreads();

        // ---- compute: 64 k-steps, unrolled by 4 ----
        for (int k4 = 0; k4 < KC; k4 += 4) {
            float4 a[4];
            #pragma unroll
            for (int rr = 0; rr < 4; ++rr)
                a[rr] = *(const float4*)(&Atile[(ty * 4 + rr) * LDT + k4]);

            #pragma unroll
            for (int kk = 0; kk < 4; ++kk) {
                const float4 b = *(const float4*)(&Btile[(k4 + kk) * LDT + tx * 4]);
                #pragma unroll
                for (int rr = 0; rr < 4; ++rr) {
                    const float av = ((const float*)&a[rr])[kk];
                    acc[rr][0] += av * b.x;
                    acc[rr][1] += av * b.y;
                    acc[rr][2] += av * b.z;
                    acc[rr][3] += av * b.w;
                }
            }
        }
    }

    // ---- epilogue: relu + guarded store ----
    #pragma unroll
    for (int rr = 0; rr < 4; ++rr) {
        const int node = m0 + ty * 4 + rr;
        if (node < N_NODES) {
            float4 v;
            v.x = fmaxf(acc[rr][0], 0.f);
            v.y = fmaxf(acc[rr][1], 0.f);
            v.z = fmaxf(acc[rr][2], 0.f);
            v.w = fmaxf(acc[rr][3], 0.f);
            *(float4*)(out + (size_t)node * D_OUT + c0 + tx * 4) = v;
        }
    }
}

extern "C" void kernel_launch(void* const* d_in, const int* in_sizes, int n_in,
                              void* d_out, int out_size, void* d_ws, size_t ws_size,
                              hipStream_t stream)
{
    const float* feat  = (const float*)d_in[0];
    const int*   edges = (const int*)d_in[1];
    const float* W     = (const float*)d_in[2];
    float*       out   = (float*)d_out;
    float*       agg   = (float*)d_ws;   // 50000*128*4 = 25.6 MB scratch

    agg_kernel<<<N_NODES / 8, 256, 0, stream>>>(feat, edges, agg);

    dim3 grid((N_NODES + TM - 1) / TM, D_OUT / TN);
    gemm_kernel<<<grid, 256, 0, stream>>>(feat, agg, W, out);
}

// Round 2
// 146.545 us; speedup vs baseline: 1.8422x; 1.8422x over previous
//
#include <hip/hip_runtime.h>

#define NN  50000
#define DEG 32
#define DF  128
#define DO  256
#define FEAT4 (NN * DF / 4)   // 1,600,000 float4 groups

typedef __bf16 bf16x8 __attribute__((ext_vector_type(8)));
typedef float  f32x4  __attribute__((ext_vector_type(4)));

__device__ __forceinline__ unsigned short f2bf(float f) {
    unsigned u = __float_as_uint(f);
    u += 0x7FFF + ((u >> 16) & 1);     // round-to-nearest-even
    return (unsigned short)(u >> 16);
}
__device__ __forceinline__ float bf2f(unsigned short h) {
    return __uint_as_float(((unsigned)h) << 16);
}

// ---------------------------------------------------------------------------
// Convert: feat fp32 -> bf16 (vectorized), W fp32 [K][N] -> Wt bf16 [N][K].
// ---------------------------------------------------------------------------
__global__ __launch_bounds__(256) void convert_kernel(
    const float* __restrict__ feat, const float* __restrict__ W,
    unsigned short* __restrict__ featb, unsigned short* __restrict__ Wt)
{
    const int gid = blockIdx.x * 256 + threadIdx.x;
    if (gid < FEAT4) {
        const float4 v = ((const float4*)feat)[gid];
        ushort4 o;
        o.x = f2bf(v.x); o.y = f2bf(v.y); o.z = f2bf(v.z); o.w = f2bf(v.w);
        ((ushort4*)featb)[gid] = o;
    } else {
        const int t = gid - FEAT4;
        if (t < DO * DO) {
            const int n = t >> 8, k = t & 255;
            Wt[n * DO + k] = f2bf(W[k * DO + n]);   // write coalesced along k
        }
    }
}

// ---------------------------------------------------------------------------
// Aggregation over bf16 table: half the fill bytes of the fp32 version.
// 8 nodes/block, 32 lanes/node, ushort4 (4 bf16) per lane, fp32 accumulate.
// ---------------------------------------------------------------------------
__global__ __launch_bounds__(256) void agg_kernel(
    const unsigned short* __restrict__ featb,
    const int*            __restrict__ edges,
    unsigned short*       __restrict__ aggb)
{
    const int node = blockIdx.x * 8 + (threadIdx.x >> 5);
    const int l    = threadIdx.x & 31;
    const int* e   = edges + node * DEG;

    float a0 = 0.f, a1 = 0.f, a2 = 0.f, a3 = 0.f;
    #pragma unroll
    for (int d = 0; d < DEG; ++d) {
        const int idx = e[d];
        const ushort4 v = *(const ushort4*)(featb + (size_t)idx * DF + l * 4);
        a0 += bf2f(v.x); a1 += bf2f(v.y); a2 += bf2f(v.z); a3 += bf2f(v.w);
    }
    const float s = 1.0f / (float)DEG;
    ushort4 o;
    o.x = f2bf(a0 * s); o.y = f2bf(a1 * s); o.z = f2bf(a2 * s); o.w = f2bf(a3 * s);
    *(ushort4*)(aggb + (size_t)node * DF + l * 4) = o;
}

// ---------------------------------------------------------------------------
// MFMA GEMM: out = relu([featb | aggb] @ W) with W pre-transposed to Wt[n][k].
// 128x128 block tile, 4 waves in 2x2, each wave 64x64 via 4x4 grid of
// 16x16x32 bf16 MFMAs. K=256 staged in 4 chunks of 64 through LDS.
// LDS rows padded to 72 bf16 (144 B = bank shift 4/row -> 2-way max, free).
// ---------------------------------------------------------------------------
#define BM  128
#define BN  128
#define LDA 72

__global__ __launch_bounds__(256) void gemm_kernel(
    const unsigned short* __restrict__ featb,
    const unsigned short* __restrict__ aggb,
    const unsigned short* __restrict__ Wt,
    float*                __restrict__ out)
{
    __shared__ __align__(16) unsigned short Asw[BM * LDA];
    __shared__ __align__(16) unsigned short Bsw[BN * LDA];

    const int tid  = threadIdx.x;
    const int m0   = blockIdx.x * BM;
    const int c0   = blockIdx.y * BN;
    const int wave = tid >> 6, lane = tid & 63;
    const int quad = lane >> 4, lr = lane & 15;
    const int wm   = (wave & 1) * 64;
    const int wn   = (wave >> 1) * 64;

    const int srow = tid >> 3;        // 0..31 staging row per pass
    const int sseg = (tid & 7) * 8;   // bf16 segment offset (8 bf16 = 16 B)

    f32x4 acc[4][4] = {};

    for (int kc = 0; kc < 4; ++kc) {
        const unsigned short* srcA = (kc < 2) ? (featb + kc * 64)
                                              : (aggb + (kc - 2) * 64);
        const unsigned short* srcB = Wt + kc * 64;

        __syncthreads();
        #pragma unroll
        for (int p = 0; p < 4; ++p) {
            const int r = p * 32 + srow;
            int node = m0 + r;
            if (node >= NN) node = NN - 1;          // clamp; stores are guarded
            const float4 va = *(const float4*)(srcA + (size_t)node * DF + sseg);
            *(float4*)(Asw + r * LDA + sseg) = va;
            const float4 vb = *(const float4*)(srcB + (size_t)(c0 + r) * DO + sseg);
            *(float4*)(Bsw + r * LDA + sseg) = vb;
        }
        __syncthreads();

        #pragma unroll
        for (int kk = 0; kk < 64; kk += 32) {
            bf16x8 af[4], bfr[4];
            #pragma unroll
            for (int i = 0; i < 4; ++i) {
                af[i]  = *(const bf16x8*)(Asw + (wm + i * 16 + lr) * LDA + kk + quad * 8);
                bfr[i] = *(const bf16x8*)(Bsw + (wn + i * 16 + lr) * LDA + kk + quad * 8);
            }
            #pragma unroll
            for (int mi = 0; mi < 4; ++mi)
                #pragma unroll
                for (int ni = 0; ni < 4; ++ni)
                    acc[mi][ni] = __builtin_amdgcn_mfma_f32_16x16x32_bf16(
                        af[mi], bfr[ni], acc[mi][ni], 0, 0, 0);
        }
    }

    // epilogue: relu + guarded store. C/D: col=lane&15, row=quad*4+reg.
    #pragma unroll
    for (int mi = 0; mi < 4; ++mi) {
        #pragma unroll
        for (int r = 0; r < 4; ++r) {
            const int row = m0 + wm + mi * 16 + quad * 4 + r;
            if (row < NN) {
                #pragma unroll
                for (int ni = 0; ni < 4; ++ni) {
                    const float v = acc[mi][ni][r];
                    out[(size_t)row * DO + c0 + wn + ni * 16 + lr] = fmaxf(v, 0.f);
                }
            }
        }
    }
}

extern "C" void kernel_launch(void* const* d_in, const int* in_sizes, int n_in,
                              void* d_out, int out_size, void* d_ws, size_t ws_size,
                              hipStream_t stream)
{
    const float* feat  = (const float*)d_in[0];
    const int*   edges = (const int*)d_in[1];
    const float* W     = (const float*)d_in[2];
    float*       out   = (float*)d_out;

    unsigned short* aggb  = (unsigned short*)d_ws;            // 12.8 MB
    unsigned short* featb = aggb  + (size_t)NN * DF;          // 12.8 MB
    unsigned short* Wt    = featb + (size_t)NN * DF;          // 128 KB

    convert_kernel<<<(FEAT4 + DO * DO + 255) / 256, 256, 0, stream>>>(feat, W, featb, Wt);
    agg_kernel<<<NN / 8, 256, 0, stream>>>(featb, edges, aggb);

    dim3 grid((NN + BM - 1) / BM, DO / BN);
    gemm_kernel<<<grid, 256, 0, stream>>>(featb, aggb, Wt, out);
}